// Round 7
// baseline (394.556 us; speedup 1.0000x reference)
//
#include <hip/hip_runtime.h>

// DiffPooling on MI355X (gfx950).
// outputs f32 concat: features_pooled (256x512), assignments (8192x256),
// adjacency_pooled (256x256), link_loss, ent_loss.
// link_loss: ||A - sp sp^T||_F^2 = sum(A^2) - 2*tr(adj_pooled) + ||sp^T sp||_F^2
//
// MFMA A-operands in "panel" format (stride-32 u16 rows, gll-linear):
//   offset_u16((b,p), m, k) = ((b*(Kin/32)+p)*256 + m%256)*32 + (k%32)
// NOTE: this round launches G2 TWICE (probe) to measure its duration via the
// total-time delta; probe writes identical partials + a dummy sumsq slot.

typedef unsigned short u16;
typedef __bf16 bf16x8 __attribute__((ext_vector_type(8)));
typedef float f32x4 __attribute__((ext_vector_type(4)));
typedef float float8_t __attribute__((ext_vector_type(8)));
typedef unsigned short ushort8_t __attribute__((ext_vector_type(8)));

#define Nn 8192
#define Dd 512
#define Kk 256

__device__ __forceinline__ u16 f2bf(float f) {
  unsigned int u = __builtin_bit_cast(unsigned int, f);
  u += 0x7FFFu + ((u >> 16) & 1u);   // RNE
  return (u16)(u >> 16);
}
__device__ __forceinline__ float bf2f(u16 h) {
  return __builtin_bit_cast(float, (unsigned int)h << 16);
}
__device__ __forceinline__ void gll16(const void* g, void* l) {
  __builtin_amdgcn_global_load_lds(
      (const __attribute__((address_space(1))) unsigned int*)g,
      (__attribute__((address_space(3))) unsigned int*)l, 16, 0, 0);
}

template <bool B> struct BRegSel { typedef float8_t T; };
template <> struct BRegSel<true> { typedef ushort8_t T; };

// ---------------- panel-A bf16 MFMA GEMM, counted-vmcnt pipeline ----------------
// C(256 x 64 per block) = Apanel @ B(row-major, ldb; f32->bf16 on the fly if !BF16B)
// 256 threads / 4 waves, wave tile 64x64, BK=32, double-buffered LDS, 40960 B LDS.
// Per step t: gllA(other, t+1)[4] ; storeB(cur, rb) [implicit wait drains A(t)+B(t)] ;
//             loadB(rb, t+1)[8] ; s_waitcnt vmcnt(12) lgkmcnt(0) ; barrier ;
//             MFMA(cur) ; barrier.  12 = gllA_next(4)+loadB_next(8) stay in flight.
// OUTKIND: 0 = f32 store via LDS (G1), 1 = bf16 z-partial via LDS (G2),
//          2 = atomic f32 (G4/G5/G3).  OCC: min blocks/CU (4 for G2).
template <bool BF16B, bool SUMSQ, int OUTKIND, int OCC>
__launch_bounds__(256, OCC)
__global__ void gemm2(const u16* __restrict__ Apan, int ppmb,
                      const void* __restrict__ Bv, int ldb,
                      void* __restrict__ Cv, int ldc,
                      int kchunk, size_t zstride,
                      float* __restrict__ sumsq, int swz) {
  __shared__ alignas(16) u16 SH[2 * 8192 + 2 * 2048];  // 40960 B exactly
  float* sred = (float*)&SH[20472];                    // last 16 B of SH

  int bx = blockIdx.x, bz = blockIdx.z;
  if (swz) {  // XCD-chunked bijective remap (total % 8 == 0)
    int gx = gridDim.x, tot = gx * gridDim.z;
    int f = bx + gx * bz;
    int l = (f & 7) * (tot >> 3) + (f >> 3);
    bx = l % gx; bz = l / gx;
  }
  const int tid = threadIdx.x, wv = tid >> 6, lane = tid & 63;
  const int l15 = lane & 15, g = lane >> 4;
  const int col0 = bx * 64;
  const int row0 = blockIdx.y * 256;
  const int kbeg = bz * kchunk;
  const int steps = kchunk >> 5;
  const u16* pbase = Apan + (size_t)(blockIdx.y * ppmb + (kbeg >> 5)) * 8192;

  float ss = 0.f;
  typename BRegSel<BF16B>::T rb;

  auto loadB = [&](int t) {   // thread owns column (col0+lane), rows wv*8..+7
    const int kq = kbeg + t * 32 + wv * 8;
    if constexpr (BF16B) {
      const u16* p = (const u16*)Bv + (size_t)kq * ldb + col0 + lane;
#pragma unroll
      for (int i = 0; i < 8; ++i) rb[i] = p[(size_t)i * ldb];
    } else {
      const float* p = (const float*)Bv + (size_t)kq * ldb + col0 + lane;
#pragma unroll
      for (int i = 0; i < 8; ++i) rb[i] = p[(size_t)i * ldb];
    }
  };
  auto storeB = [&](int buf) {  // pack 8 k-elems of one col -> one b128
    ushort8_t h;
    if constexpr (BF16B) {
      h = rb;
    } else {
#pragma unroll
      for (int i = 0; i < 8; ++i) {
        h[i] = f2bf(rb[i]);
        if constexpr (SUMSQ) ss += rb[i] * rb[i];
      }
    }
    *(uint4*)&SH[16384 + buf * 2048 + lane * 32 + wv * 8] = __builtin_bit_cast(uint4, h);
  };
  auto gllA = [&](int buf, int t) {      // 16 KB panel tile -> LDS, linear, coalesced
    const char* gp = (const char*)(pbase + (size_t)t * 8192) + wv * 4096 + lane * 16;
    char* lp = (char*)&SH[buf * 8192] + wv * 4096;
#pragma unroll
    for (int r = 0; r < 4; ++r) gll16(gp + r * 1024, lp + r * 1024);
  };

  f32x4 acc[4][4];
#pragma unroll
  for (int i = 0; i < 4; ++i)
#pragma unroll
    for (int j = 0; j < 4; ++j) acc[i][j] = (f32x4){0.f, 0.f, 0.f, 0.f};

  auto comp = [&](int buf) {
    const u16* as = &SH[buf * 8192];
    const u16* bs = &SH[16384 + buf * 2048];
    bf16x8 afr[4], bfr[4];
#pragma unroll
    for (int j = 0; j < 4; ++j)
      bfr[j] = *(const bf16x8*)(bs + (j * 16 + l15) * 32 + g * 8);
#pragma unroll
    for (int i = 0; i < 4; ++i)
      afr[i] = *(const bf16x8*)(as + (wv * 64 + i * 16 + l15) * 32 + g * 8);
#pragma unroll
    for (int i = 0; i < 4; ++i)
#pragma unroll
      for (int j = 0; j < 4; ++j)
        acc[i][j] = __builtin_amdgcn_mfma_f32_16x16x32_bf16(afr[i], bfr[j], acc[i][j], 0, 0, 0);
  };

  // prologue: A(0), B(0) in flight
  gllA(0, 0);
  loadB(0);
  const int last = steps - 1;

  for (int t = 0; t < steps; ++t) {
    const int cur = t & 1;
    gllA(1 - cur, (t + 1 < last) ? t + 1 : last);
    storeB(cur);                          // implicit wait: drains A(t)+B(t)
    loadB((t + 1 < last) ? t + 1 : last);
    asm volatile("s_waitcnt vmcnt(12) lgkmcnt(0)" ::: "memory");
    __builtin_amdgcn_s_barrier();
    __builtin_amdgcn_sched_barrier(0);
    comp(cur);
    __builtin_amdgcn_sched_barrier(0);
    __builtin_amdgcn_s_barrier();
  }
  // full drain before LDS reuse in epilogues
  asm volatile("s_waitcnt vmcnt(0) lgkmcnt(0)" ::: "memory");
  __builtin_amdgcn_s_barrier();

  // epilogues (C/D layout m89-verified: col = j*16+l15, row = wv*64+i*16+g*4+r)
  if constexpr (OUTKIND == 0) {          // f32 via LDS, two 128-row halves
    float* sf = (float*)SH;              // [128][68] f32 (34816 B)
#pragma unroll
    for (int h = 0; h < 2; ++h) {
      __syncthreads();
      if ((wv >> 1) == h) {
#pragma unroll
        for (int i = 0; i < 4; ++i)
#pragma unroll
          for (int j = 0; j < 4; ++j)
#pragma unroll
            for (int r = 0; r < 4; ++r)
              sf[((wv & 1) * 64 + i * 16 + g * 4 + r) * 68 + j * 16 + l15] = acc[i][j][r];
      }
      __syncthreads();
#pragma unroll
      for (int e = 0; e < 8; ++e) {     // 2048 float4s = full 128x64 tile
        int idx2 = tid + e * 256;
        int m = idx2 >> 4, c4 = (idx2 & 15) * 4;
        float4 v = *(const float4*)(sf + m * 68 + c4);
        *(float4*)((float*)Cv + (size_t)(row0 + h * 128 + m) * ldc + col0 + c4) = v;
      }
    }
  } else if constexpr (OUTKIND == 1) {   // bf16 z-partial via LDS
    u16* C = (u16*)Cv + (size_t)bz * zstride;
    u16* sb = SH;                        // [256][72] u16 (36864 B)
#pragma unroll
    for (int i = 0; i < 4; ++i)
#pragma unroll
      for (int j = 0; j < 4; ++j)
#pragma unroll
        for (int r = 0; r < 4; ++r)
          sb[(wv * 64 + i * 16 + g * 4 + r) * 72 + j * 16 + l15] = f2bf(acc[i][j][r]);
    __syncthreads();
#pragma unroll
    for (int e = 0; e < 8; ++e) {
      int m = (tid >> 3) + e * 32;
      uint4 v = *(const uint4*)(sb + m * 72 + (tid & 7) * 8);
      *(uint4*)(C + (size_t)m * ldc + col0 + (tid & 7) * 8) = v;
    }
  } else {                               // atomic f32
    float* C = (float*)Cv;
#pragma unroll
    for (int i = 0; i < 4; ++i)
#pragma unroll
      for (int j = 0; j < 4; ++j) {
        size_t base = (size_t)(row0 + wv * 64 + i * 16 + g * 4) * ldc + col0 + j * 16 + l15;
#pragma unroll
        for (int r = 0; r < 4; ++r) atomicAdd(C + base + (size_t)r * ldc, acc[i][j][r]);
      }
  }

  if constexpr (SUMSQ) {
#pragma unroll
    for (int o = 32; o; o >>= 1) ss += __shfl_xor(ss, o);
    __syncthreads();                     // sred region reuse is safe (disjoint bytes)
    if (lane == 0) sred[wv] = ss;
    __syncthreads();
    if (tid == 0) atomicAdd(sumsq, sred[0] + sred[1] + sred[2] + sred[3]);
  }
}

// ---------------- producers / small kernels ----------------
// one kernel zeroes fpool, apool, spTsp, cs, scal (replaces 5 memsets)
__launch_bounds__(256)
__global__ void zero_misc(float* __restrict__ fpool, float* __restrict__ apool,
                          float* __restrict__ spTsp, float* __restrict__ cs,
                          float* __restrict__ scal) {
  int i = blockIdx.x * 256 + threadIdx.x;
  float4 z = {0.f, 0.f, 0.f, 0.f};
  if (i < 32768)       ((float4*)fpool)[i] = z;
  else if (i < 49152)  ((float4*)apool)[i - 32768] = z;
  else if (i < 65536)  ((float4*)spTsp)[i - 49152] = z;
  else if (i < 65600)  ((float4*)cs)[i - 65536] = z;
  else if (i == 65600) ((float4*)scal)[0] = z;
}

__launch_bounds__(256)
__global__ void cvtF_panel(const float* __restrict__ F, u16* __restrict__ pan) {
  int idx = blockIdx.x * 256 + threadIdx.x;      // 524288 groups of 8
  int m = idx >> 6, k0 = (idx & 63) * 8;
  float4 a = *(const float4*)(F + (size_t)m * Dd + k0);
  float4 b = *(const float4*)(F + (size_t)m * Dd + k0 + 4);
  ushort8_t h;
  h[0] = f2bf(a.x); h[1] = f2bf(a.y); h[2] = f2bf(a.z); h[3] = f2bf(a.w);
  h[4] = f2bf(b.x); h[5] = f2bf(b.y); h[6] = f2bf(b.z); h[7] = f2bf(b.w);
  int mb = m >> 8, mr = m & 255, p = k0 >> 5, c = k0 & 31;
  *(uint4*)(pan + ((size_t)(mb * 16 + p) * 256 + mr) * 32 + c) = __builtin_bit_cast(uint4, h);
}

__launch_bounds__(256)
__global__ void softmax_rows(float* __restrict__ io, const float* __restrict__ bias) {
  __shared__ float s1[4], s2[4];
  int n = blockIdx.x, k = threadIdx.x, w = k >> 6;
  size_t idx = (size_t)n * Kk + k;
  float x = io[idx] + bias[k];
  float m = x;
#pragma unroll
  for (int o = 32; o; o >>= 1) m = fmaxf(m, __shfl_xor(m, o));
  if ((k & 63) == 0) s1[w] = m;
  __syncthreads();
  m = fmaxf(fmaxf(s1[0], s1[1]), fmaxf(s1[2], s1[3]));
  float e = __expf(x - m);
  float sum = e;
#pragma unroll
  for (int o = 32; o; o >>= 1) sum += __shfl_xor(sum, o);
  if ((k & 63) == 0) s2[w] = sum;
  __syncthreads();
  sum = s2[0] + s2[1] + s2[2] + s2[3];
  io[idx] = e / sum;
}

__launch_bounds__(256)
__global__ void colsum_k(const float* __restrict__ a, float* __restrict__ cs) {
  int k = threadIdx.x;
  size_t n0 = (size_t)blockIdx.x * 32;
  float s = 0.f;
  for (int i = 0; i < 32; ++i) s += a[(n0 + i) * Kk + k];
  atomicAdd(&cs[k], s);
}

// fused: sp (bf16 row-major) + spT panel + entropy. block p: rows [32p,32p+32).
__launch_bounds__(256)
__global__ void make_sp_all(const float* __restrict__ a, const float* __restrict__ cs,
                            u16* __restrict__ spb, u16* __restrict__ pan,
                            float* __restrict__ ent_sum) {
  __shared__ float sr[4];
  int p = blockIdx.x, k = threadIdx.x;
  float inv = 1.f / (cs[k] + 1e-8f);
  int n0 = p * 32;
  float ent = 0.f;
  ushort8_t h[4];
#pragma unroll
  for (int q = 0; q < 4; ++q) {
#pragma unroll
    for (int j = 0; j < 8; ++j) {
      float v = a[(size_t)(n0 + q * 8 + j) * Kk + k] * inv;
      u16 hb = f2bf(v);
      h[q][j] = hb;
      ent -= v * __logf(v + 1e-15f);
      spb[(size_t)(n0 + q * 8 + j) * Kk + k] = hb;
    }
  }
  u16* dst = pan + ((size_t)p * 256 + k) * 32;
  *(uint4*)(dst + 0)  = __builtin_bit_cast(uint4, h[0]);
  *(uint4*)(dst + 8)  = __builtin_bit_cast(uint4, h[1]);
  *(uint4*)(dst + 16) = __builtin_bit_cast(uint4, h[2]);
  *(uint4*)(dst + 24) = __builtin_bit_cast(uint4, h[3]);
#pragma unroll
  for (int o = 32; o; o >>= 1) ent += __shfl_xor(ent, o);
  if ((k & 63) == 0) sr[k >> 6] = ent;
  __syncthreads();
  if (k == 0) atomicAdd(ent_sum, sr[0] + sr[1] + sr[2] + sr[3]);
}

// sum 8 bf16 partials -> P panel (stride-32)
__launch_bounds__(256)
__global__ void combine_P(const u16* __restrict__ part, u16* __restrict__ pan) {
  int idx = blockIdx.x * 256 + threadIdx.x;      // 262144
  int m = idx >> 10, kk8 = idx & 1023;
  size_t off = (size_t)m * Nn + kk8 * 8;
  float8_t s = {0.f, 0.f, 0.f, 0.f, 0.f, 0.f, 0.f, 0.f};
#pragma unroll
  for (int z = 0; z < 8; ++z) {
    ushort8_t v = __builtin_bit_cast(ushort8_t,
        *(const uint4*)(part + (size_t)z * Kk * Nn + off));
#pragma unroll
    for (int j = 0; j < 8; ++j) s[j] += bf2f(v[j]);
  }
  ushort8_t h;
#pragma unroll
  for (int j = 0; j < 8; ++j) h[j] = f2bf(s[j]);
  int p = kk8 >> 2, c = (kk8 & 3) * 8;
  *(uint4*)(pan + ((size_t)p * 256 + m) * 32 + c) = __builtin_bit_cast(uint4, h);
}

__launch_bounds__(256)
__global__ void finalize_k(const float* __restrict__ ap, const float* __restrict__ spTsp,
                           const float* __restrict__ scal,
                           float* __restrict__ olink, float* __restrict__ oent) {
  __shared__ float s1[4], s2[4];
  int t = threadIdx.x;
  float tr = ap[t * (Kk + 1)];
#pragma unroll
  for (int o = 32; o; o >>= 1) tr += __shfl_xor(tr, o);
  if ((t & 63) == 0) s1[t >> 6] = tr;
  __syncthreads();
  float trace = s1[0] + s1[1] + s1[2] + s1[3];
  float fr = 0.f;
  for (int i = t; i < Kk * Kk; i += 256) { float v = spTsp[i]; fr += v * v; }
#pragma unroll
  for (int o = 32; o; o >>= 1) fr += __shfl_xor(fr, o);
  if ((t & 63) == 0) s2[t >> 6] = fr;
  __syncthreads();
  float fro = s2[0] + s2[1] + s2[2] + s2[3];
  if (t == 0) {
    float val = scal[0] - 2.f * trace + fro;
    *olink = sqrtf(fmaxf(val, 0.f)) / ((float)Nn * (float)Nn);
    *oent  = scal[1] / (float)Nn;
  }
}

// ---------------- launch ----------------
extern "C" void kernel_launch(void* const* d_in, const int* in_sizes, int n_in,
                              void* d_out, int out_size, void* d_ws, size_t ws_size,
                              hipStream_t stream) {
  const float* F    = (const float*)d_in[0];
  const float* Adj  = (const float*)d_in[1];
  const float* W    = (const float*)d_in[2];
  const float* bias = (const float*)d_in[3];
  float* out = (float*)d_out;
  char* ws = (char*)d_ws;

  u16*  FbfPan = (u16*)(ws + 0);           // 8 MB (dead after G1; overlaid by parts)
  u16*  parts  = (u16*)(ws + 0);           // 8 x 4 MB bf16 partials (32 MB)
  u16*  spb    = (u16*)(ws + 33554432);    // 4 MB
  u16*  spTpan = (u16*)(ws + 37748736);    // 4 MB
  u16*  Ppan   = (u16*)(ws + 41943040);    // 4 MB
  float* cs    = (float*)(ws + 46137344);  // 1 KB
  float* spTsp = (float*)(ws + 46138368);  // 256 KB
  float* scal  = (float*)(ws + 46400512);  // [0]=sumA2 [1]=ent [2]=probe dummy [3]=pad

  float* fpool  = out;
  float* assign = out + 131072;
  float* apool  = out + 2228224;
  float* olink  = out + 2293760;
  float* oent   = out + 2293761;

  zero_misc<<<257, 256, 0, stream>>>(fpool, apool, spTsp, cs, scal);
  cvtF_panel<<<2048, 256, 0, stream>>>(F, FbfPan);

  // G1: logits = F @ W (W f32 converted on the fly) -> assign, softmax in place
  gemm2<false, false, 0, 2><<<dim3(4, 32, 1), 256, 0, stream>>>(
      FbfPan, 16, W, Kk, assign, Kk, Dd, 0, nullptr, 0);
  softmax_rows<<<Nn, 256, 0, stream>>>(assign, bias);
  colsum_k<<<256, 256, 0, stream>>>(assign, cs);
  make_sp_all<<<256, 256, 0, stream>>>(assign, cs, spb, spTpan, &scal[1]);

  // G4: features_pooled = spT @ F (atomic over 16 k-chunks; XCD-chunked)
  gemm2<false, false, 2, 2><<<dim3(8, 1, 16), 256, 0, stream>>>(
      spTpan, 256, F, Dd, fpool, Dd, Nn / 16, 0, nullptr, 1);
  // G5: spTsp = spT @ sp
  gemm2<true, false, 2, 2><<<dim3(4, 1, 16), 256, 0, stream>>>(
      spTpan, 256, spb, Kk, spTsp, Kk, Nn / 16, 0, nullptr, 1);
  // G2 PROBE: identical work, dummy sumsq -> measures G2 via total-time delta
  gemm2<false, true, 1, 4><<<dim3(128, 1, 8), 256, 0, stream>>>(
      spTpan, 256, Adj, Nn, parts, Nn, Nn / 8, (size_t)Kk * Nn, &scal[2], 1);
  // G2: P = spT @ A: 8 bf16 partials + fused sum(A^2), XCD-chunked, 4 blk/CU
  gemm2<false, true, 1, 4><<<dim3(128, 1, 8), 256, 0, stream>>>(
      spTpan, 256, Adj, Nn, parts, Nn, Nn / 8, (size_t)Kk * Nn, &scal[0], 1);
  combine_P<<<1024, 256, 0, stream>>>(parts, Ppan);
  // G3: adjacency_pooled = P @ sp
  gemm2<true, false, 2, 2><<<dim3(4, 1, 16), 256, 0, stream>>>(
      Ppan, 256, spb, Kk, apool, Kk, Nn / 16, 0, nullptr, 1);

  finalize_k<<<1, 256, 0, stream>>>(apool, spTsp, scal, olink, oent);
}

// Round 8
// 204.461 us; speedup vs baseline: 1.9297x; 1.9297x over previous
//
#include <hip/hip_runtime.h>

// DiffPooling on MI355X (gfx950).
// outputs f32 concat: features_pooled (256x512), assignments (8192x256),
// adjacency_pooled (256x256), link_loss, ent_loss.
// link_loss: ||A - sp sp^T||_F^2 = sum(A^2) - 2*tr(adj_pooled) + ||sp^T sp||_F^2
//
// MFMA A-operands in "panel" format (stride-32 u16 rows, gll-linear):
//   offset_u16((b,p), m, k) = ((b*(Kin/32)+p)*256 + m%256)*32 + (k%32)
// Mid-size GEMMs (G4/G5/G3) write f32 z-partials (plain coalesced stores, no
// atomics); combine3 reduces them + computes frob/trace scalars.

typedef unsigned short u16;
typedef __bf16 bf16x8 __attribute__((ext_vector_type(8)));
typedef float f32x4 __attribute__((ext_vector_type(4)));
typedef float float8_t __attribute__((ext_vector_type(8)));
typedef unsigned short ushort8_t __attribute__((ext_vector_type(8)));

#define Nn 8192
#define Dd 512
#define Kk 256

__device__ __forceinline__ u16 f2bf(float f) {
  unsigned int u = __builtin_bit_cast(unsigned int, f);
  u += 0x7FFFu + ((u >> 16) & 1u);   // RNE
  return (u16)(u >> 16);
}
__device__ __forceinline__ float bf2f(u16 h) {
  return __builtin_bit_cast(float, (unsigned int)h << 16);
}
__device__ __forceinline__ void gll16(const void* g, void* l) {
  __builtin_amdgcn_global_load_lds(
      (const __attribute__((address_space(1))) unsigned int*)g,
      (__attribute__((address_space(3))) unsigned int*)l, 16, 0, 0);
}

template <bool B> struct BRegSel { typedef float8_t T; };
template <> struct BRegSel<true> { typedef ushort8_t T; };

// ---------------- panel-A bf16 MFMA GEMM, counted-vmcnt pipeline ----------------
// C(256 x 64 per block) = Apanel @ B(row-major, ldb; f32->bf16 on the fly if !BF16B)
// 256 threads / 4 waves, wave tile 64x64, BK=32, double-buffered LDS, 40960 B.
// Per step t: gllA(other, t+1)[4] ; storeB(cur) [implicit wait drains B(t)+A(t)] ;
//             loadB(t+1)[8] ; s_waitcnt vmcnt(12) lgkmcnt(0) ; barrier ;
//             MFMA(cur) ; barrier.
// OUTKIND: 0 = f32 store via LDS at Cv + bz*zstride (G1 zstride=0, G4/G5/G3
//              z-partials), 1 = bf16 z-partial via LDS (G2).
template <bool BF16B, bool SUMSQ, int OUTKIND, int OCC>
__launch_bounds__(256, OCC)
__global__ void gemm2(const u16* __restrict__ Apan, int ppmb,
                      const void* __restrict__ Bv, int ldb,
                      void* __restrict__ Cv, int ldc,
                      int kchunk, size_t zstride,
                      float* __restrict__ sumsq, int swz) {
  __shared__ alignas(16) u16 SH[2 * 8192 + 2 * 2048];  // 40960 B exactly
  float* sred = (float*)&SH[20472];                    // last 16 B of SH

  int bx = blockIdx.x, bz = blockIdx.z;
  if (swz) {  // XCD-chunked bijective remap (total % 8 == 0)
    int gx = gridDim.x, tot = gx * gridDim.z;
    int f = bx + gx * bz;
    int l = (f & 7) * (tot >> 3) + (f >> 3);
    bx = l % gx; bz = l / gx;
  }
  const int tid = threadIdx.x, wv = tid >> 6, lane = tid & 63;
  const int l15 = lane & 15, g = lane >> 4;
  const int col0 = bx * 64;
  const int row0 = blockIdx.y * 256;
  const int kbeg = bz * kchunk;
  const int steps = kchunk >> 5;
  const u16* pbase = Apan + (size_t)(blockIdx.y * ppmb + (kbeg >> 5)) * 8192;

  float ss = 0.f;
  typename BRegSel<BF16B>::T rb;

  auto loadB = [&](int t) {   // thread owns column (col0+lane), rows wv*8..+7
    const int kq = kbeg + t * 32 + wv * 8;
    if constexpr (BF16B) {
      const u16* p = (const u16*)Bv + (size_t)kq * ldb + col0 + lane;
#pragma unroll
      for (int i = 0; i < 8; ++i) rb[i] = p[(size_t)i * ldb];
    } else {
      const float* p = (const float*)Bv + (size_t)kq * ldb + col0 + lane;
#pragma unroll
      for (int i = 0; i < 8; ++i) rb[i] = p[(size_t)i * ldb];
    }
  };
  auto storeB = [&](int buf) {  // pack 8 k-elems of one col -> one b128
    ushort8_t h;
    if constexpr (BF16B) {
      h = rb;
    } else {
#pragma unroll
      for (int i = 0; i < 8; ++i) {
        h[i] = f2bf(rb[i]);
        if constexpr (SUMSQ) ss += rb[i] * rb[i];
      }
    }
    *(uint4*)&SH[16384 + buf * 2048 + lane * 32 + wv * 8] = __builtin_bit_cast(uint4, h);
  };
  auto gllA = [&](int buf, int t) {      // 16 KB panel tile -> LDS, linear, coalesced
    const char* gp = (const char*)(pbase + (size_t)t * 8192) + wv * 4096 + lane * 16;
    char* lp = (char*)&SH[buf * 8192] + wv * 4096;
#pragma unroll
    for (int r = 0; r < 4; ++r) gll16(gp + r * 1024, lp + r * 1024);
  };

  f32x4 acc[4][4];
#pragma unroll
  for (int i = 0; i < 4; ++i)
#pragma unroll
    for (int j = 0; j < 4; ++j) acc[i][j] = (f32x4){0.f, 0.f, 0.f, 0.f};

  auto comp = [&](int buf) {
    const u16* as = &SH[buf * 8192];
    const u16* bs = &SH[16384 + buf * 2048];
    bf16x8 afr[4], bfr[4];
#pragma unroll
    for (int j = 0; j < 4; ++j)
      bfr[j] = *(const bf16x8*)(bs + (j * 16 + l15) * 32 + g * 8);
#pragma unroll
    for (int i = 0; i < 4; ++i)
      afr[i] = *(const bf16x8*)(as + (wv * 64 + i * 16 + l15) * 32 + g * 8);
#pragma unroll
    for (int i = 0; i < 4; ++i)
#pragma unroll
      for (int j = 0; j < 4; ++j)
        acc[i][j] = __builtin_amdgcn_mfma_f32_16x16x32_bf16(afr[i], bfr[j], acc[i][j], 0, 0, 0);
  };

  // prologue: A(0), B(0) in flight
  gllA(0, 0);
  loadB(0);
  const int last = steps - 1;

  for (int t = 0; t < steps; ++t) {
    const int cur = t & 1;
    gllA(1 - cur, (t + 1 < last) ? t + 1 : last);
    storeB(cur);                          // implicit wait: drains A(t)+B(t)
    loadB((t + 1 < last) ? t + 1 : last);
    asm volatile("s_waitcnt vmcnt(12) lgkmcnt(0)" ::: "memory");
    __builtin_amdgcn_s_barrier();
    __builtin_amdgcn_sched_barrier(0);
    comp(cur);
    __builtin_amdgcn_sched_barrier(0);
    __builtin_amdgcn_s_barrier();
  }
  // full drain before LDS reuse in epilogues
  asm volatile("s_waitcnt vmcnt(0) lgkmcnt(0)" ::: "memory");
  __builtin_amdgcn_s_barrier();

  // epilogues (C/D layout m89-verified: col = j*16+l15, row = wv*64+i*16+g*4+r)
  if constexpr (OUTKIND == 0) {          // f32 via LDS, two 128-row halves
    float* Cz = (float*)Cv + (size_t)bz * zstride;
    float* sf = (float*)SH;              // [128][68] f32 (34816 B)
#pragma unroll
    for (int h = 0; h < 2; ++h) {
      __syncthreads();
      if ((wv >> 1) == h) {
#pragma unroll
        for (int i = 0; i < 4; ++i)
#pragma unroll
          for (int j = 0; j < 4; ++j)
#pragma unroll
            for (int r = 0; r < 4; ++r)
              sf[((wv & 1) * 64 + i * 16 + g * 4 + r) * 68 + j * 16 + l15] = acc[i][j][r];
      }
      __syncthreads();
#pragma unroll
      for (int e = 0; e < 8; ++e) {     // 2048 float4s = full 128x64 tile
        int idx2 = tid + e * 256;
        int m = idx2 >> 4, c4 = (idx2 & 15) * 4;
        float4 v = *(const float4*)(sf + m * 68 + c4);
        *(float4*)(Cz + (size_t)(row0 + h * 128 + m) * ldc + col0 + c4) = v;
      }
    }
  } else {                               // bf16 z-partial via LDS (G2)
    u16* C = (u16*)Cv + (size_t)bz * zstride;
    u16* sb = SH;                        // [256][72] u16 (36864 B)
#pragma unroll
    for (int i = 0; i < 4; ++i)
#pragma unroll
      for (int j = 0; j < 4; ++j)
#pragma unroll
        for (int r = 0; r < 4; ++r)
          sb[(wv * 64 + i * 16 + g * 4 + r) * 72 + j * 16 + l15] = f2bf(acc[i][j][r]);
    __syncthreads();
#pragma unroll
    for (int e = 0; e < 8; ++e) {
      int m = (tid >> 3) + e * 32;
      uint4 v = *(const uint4*)(sb + m * 72 + (tid & 7) * 8);
      *(uint4*)(C + (size_t)m * ldc + col0 + (tid & 7) * 8) = v;
    }
  }

  if constexpr (SUMSQ) {
#pragma unroll
    for (int o = 32; o; o >>= 1) ss += __shfl_xor(ss, o);
    __syncthreads();
    if (lane == 0) sred[wv] = ss;
    __syncthreads();
    if (tid == 0) atomicAdd(sumsq, sred[0] + sred[1] + sred[2] + sred[3]);
  }
}

// ---------------- producers / small kernels ----------------
// F f32 -> panel bf16; extra last block zeroes cs + scal
__launch_bounds__(256)
__global__ void cvtF_panel(const float* __restrict__ F, u16* __restrict__ pan,
                           float* __restrict__ cs, float* __restrict__ scal) {
  if (blockIdx.x == 2048) {
    int t = threadIdx.x;
    float4 z = {0.f, 0.f, 0.f, 0.f};
    if (t < 64) ((float4*)cs)[t] = z;
    else if (t == 64) ((float4*)scal)[0] = z;   // scal[0..3]
    return;
  }
  int idx = blockIdx.x * 256 + threadIdx.x;      // 524288 groups of 8
  int m = idx >> 6, k0 = (idx & 63) * 8;
  float4 a = *(const float4*)(F + (size_t)m * Dd + k0);
  float4 b = *(const float4*)(F + (size_t)m * Dd + k0 + 4);
  ushort8_t h;
  h[0] = f2bf(a.x); h[1] = f2bf(a.y); h[2] = f2bf(a.z); h[3] = f2bf(a.w);
  h[4] = f2bf(b.x); h[5] = f2bf(b.y); h[6] = f2bf(b.z); h[7] = f2bf(b.w);
  int mb = m >> 8, mr = m & 255, p = k0 >> 5, c = k0 & 31;
  *(uint4*)(pan + ((size_t)(mb * 16 + p) * 256 + mr) * 32 + c) = __builtin_bit_cast(uint4, h);
}

// wave-per-row softmax: block = 4 waves = 4 rows; lane holds 4 cols (float4).
__launch_bounds__(256)
__global__ void softmax_rows(float* __restrict__ io, const float* __restrict__ bias) {
  int wv = threadIdx.x >> 6, lane = threadIdx.x & 63;
  int n = blockIdx.x * 4 + wv;
  float4 b4 = ((const float4*)bias)[lane];
  float4 x = ((const float4*)(io + (size_t)n * Kk))[lane];
  x.x += b4.x; x.y += b4.y; x.z += b4.z; x.w += b4.w;
  float m = fmaxf(fmaxf(x.x, x.y), fmaxf(x.z, x.w));
#pragma unroll
  for (int o = 32; o; o >>= 1) m = fmaxf(m, __shfl_xor(m, o));
  float4 e = {__expf(x.x - m), __expf(x.y - m), __expf(x.z - m), __expf(x.w - m)};
  float s = e.x + e.y + e.z + e.w;
#pragma unroll
  for (int o = 32; o; o >>= 1) s += __shfl_xor(s, o);
  float inv = 1.f / s;
  e.x *= inv; e.y *= inv; e.z *= inv; e.w *= inv;
  ((float4*)(io + (size_t)n * Kk))[lane] = e;
}

// colsum: 64 blocks x 128 rows; thread (rg = t>>6, c4 = (t&63)*4); float4.
__launch_bounds__(256)
__global__ void colsum_k(const float* __restrict__ a, float* __restrict__ cs) {
  __shared__ float4 red[4][64];
  int t = threadIdx.x, rg = t >> 6, c = t & 63;
  size_t n0 = (size_t)blockIdx.x * 128 + rg * 32;
  float4 s = {0.f, 0.f, 0.f, 0.f};
  for (int i = 0; i < 32; ++i) {
    float4 v = ((const float4*)(a + (n0 + i) * Kk))[c];
    s.x += v.x; s.y += v.y; s.z += v.z; s.w += v.w;
  }
  red[rg][c] = s;
  __syncthreads();
  if (rg == 0) {
    float4 a1 = red[1][c], a2 = red[2][c], a3 = red[3][c];
    s.x += a1.x + a2.x + a3.x; s.y += a1.y + a2.y + a3.y;
    s.z += a1.z + a2.z + a3.z; s.w += a1.w + a2.w + a3.w;
    atomicAdd(&cs[c * 4 + 0], s.x); atomicAdd(&cs[c * 4 + 1], s.y);
    atomicAdd(&cs[c * 4 + 2], s.z); atomicAdd(&cs[c * 4 + 3], s.w);
  }
}

// fused: sp (bf16 row-major) + spT panel + entropy. block p: rows [32p,32p+32).
__launch_bounds__(256)
__global__ void make_sp_all(const float* __restrict__ a, const float* __restrict__ cs,
                            u16* __restrict__ spb, u16* __restrict__ pan,
                            float* __restrict__ ent_sum) {
  __shared__ float sr[4];
  int p = blockIdx.x, k = threadIdx.x;
  float inv = 1.f / (cs[k] + 1e-8f);
  int n0 = p * 32;
  float ent = 0.f;
  ushort8_t h[4];
#pragma unroll
  for (int q = 0; q < 4; ++q) {
#pragma unroll
    for (int j = 0; j < 8; ++j) {
      float v = a[(size_t)(n0 + q * 8 + j) * Kk + k] * inv;
      u16 hb = f2bf(v);
      h[q][j] = hb;
      ent -= v * __logf(v + 1e-15f);
      spb[(size_t)(n0 + q * 8 + j) * Kk + k] = hb;
    }
  }
  u16* dst = pan + ((size_t)p * 256 + k) * 32;
  *(uint4*)(dst + 0)  = __builtin_bit_cast(uint4, h[0]);
  *(uint4*)(dst + 8)  = __builtin_bit_cast(uint4, h[1]);
  *(uint4*)(dst + 16) = __builtin_bit_cast(uint4, h[2]);
  *(uint4*)(dst + 24) = __builtin_bit_cast(uint4, h[3]);
#pragma unroll
  for (int o = 32; o; o >>= 1) ent += __shfl_xor(ent, o);
  if ((k & 63) == 0) sr[k >> 6] = ent;
  __syncthreads();
  if (k == 0) atomicAdd(ent_sum, sr[0] + sr[1] + sr[2] + sr[3]);
}

// sum 8 bf16 partials -> P panel (stride-32)
__launch_bounds__(256)
__global__ void combine_P(const u16* __restrict__ part, u16* __restrict__ pan) {
  int idx = blockIdx.x * 256 + threadIdx.x;      // 262144
  int m = idx >> 10, kk8 = idx & 1023;
  size_t off = (size_t)m * Nn + kk8 * 8;
  float8_t s = {0.f, 0.f, 0.f, 0.f, 0.f, 0.f, 0.f, 0.f};
#pragma unroll
  for (int z = 0; z < 8; ++z) {
    ushort8_t v = __builtin_bit_cast(ushort8_t,
        *(const uint4*)(part + (size_t)z * Kk * Nn + off));
#pragma unroll
    for (int j = 0; j < 8; ++j) s[j] += bf2f(v[j]);
  }
  ushort8_t h;
#pragma unroll
  for (int j = 0; j < 8; ++j) h[j] = f2bf(s[j]);
  int p = kk8 >> 2, c = (kk8 & 3) * 8;
  *(uint4*)(pan + ((size_t)p * 256 + m) * 32 + c) = __builtin_bit_cast(uint4, h);
}

// sum 16 f32 z-partials: blocks 0-511 fpool; 512-767 spTsp->frob into scal[2];
// 768-1023 apool (+trace into scal[3]).
__launch_bounds__(256)
__global__ void combine3(const float* __restrict__ fp_part, const float* __restrict__ ss_part,
                         const float* __restrict__ ap_part,
                         float* __restrict__ fpool, float* __restrict__ apool,
                         float* __restrict__ scal) {
  __shared__ float sr[4];
  int b = blockIdx.x, t = threadIdx.x;
  if (b < 512) {
    int i = b * 256 + t;
    float s = 0.f;
#pragma unroll
    for (int z = 0; z < 16; ++z) s += fp_part[z * 131072 + i];
    fpool[i] = s;
  } else if (b < 768) {
    int i = (b - 512) * 256 + t;
    float s = 0.f;
#pragma unroll
    for (int z = 0; z < 16; ++z) s += ss_part[z * 65536 + i];
    float q = s * s;
#pragma unroll
    for (int o = 32; o; o >>= 1) q += __shfl_xor(q, o);
    if ((t & 63) == 0) sr[t >> 6] = q;
    __syncthreads();
    if (t == 0) atomicAdd(&scal[2], sr[0] + sr[1] + sr[2] + sr[3]);
  } else {
    int i = (b - 768) * 256 + t;
    float s = 0.f;
#pragma unroll
    for (int z = 0; z < 16; ++z) s += ap_part[z * 65536 + i];
    apool[i] = s;
    if (i % 257 == 0) atomicAdd(&scal[3], s);
  }
}

__launch_bounds__(64)
__global__ void finalize_k(const float* __restrict__ scal,
                           float* __restrict__ olink, float* __restrict__ oent) {
  if (threadIdx.x == 0) {
    float val = scal[0] - 2.f * scal[3] + scal[2];
    *olink = sqrtf(fmaxf(val, 0.f)) / ((float)Nn * (float)Nn);
    *oent  = scal[1] / (float)Nn;
  }
}

// ---------------- launch ----------------
extern "C" void kernel_launch(void* const* d_in, const int* in_sizes, int n_in,
                              void* d_out, int out_size, void* d_ws, size_t ws_size,
                              hipStream_t stream) {
  const float* F    = (const float*)d_in[0];
  const float* Adj  = (const float*)d_in[1];
  const float* W    = (const float*)d_in[2];
  const float* bias = (const float*)d_in[3];
  float* out = (float*)d_out;
  char* ws = (char*)d_ws;

  u16*  FbfPan  = (u16*)(ws + 0);           // 8 MB (dead after G1; overlaid by parts)
  u16*  parts   = (u16*)(ws + 0);           // 8 x 4 MB bf16 G2 partials (32 MB)
  u16*  spb     = (u16*)(ws + 33554432);    // 4 MB
  u16*  spTpan  = (u16*)(ws + 37748736);    // 4 MB
  u16*  Ppan    = (u16*)(ws + 41943040);    // 4 MB
  float* fp_part = (float*)(ws + 46137344); // 8 MB (16 x 131072 f32)
  float* ss_part = (float*)(ws + 54525952); // 4 MB (16 x 65536 f32)
  float* ap_part = (float*)(ws + 58720256); // 4 MB (16 x 65536 f32)
  float* cs     = (float*)(ws + 62914560);  // 1 KB
  float* scal   = (float*)(ws + 62915584);  // [0]=sumA2 [1]=ent [2]=frob [3]=trace

  float* fpool  = out;
  float* assign = out + 131072;
  float* apool  = out + 2228224;
  float* olink  = out + 2293760;
  float* oent   = out + 2293761;

  cvtF_panel<<<2049, 256, 0, stream>>>(F, FbfPan, cs, scal);

  // G1: logits = F @ W (W f32 converted on the fly) -> assign, softmax in place
  gemm2<false, false, 0, 2><<<dim3(4, 32, 1), 256, 0, stream>>>(
      FbfPan, 16, W, Kk, assign, Kk, Dd, 0, nullptr, 0);
  softmax_rows<<<2048, 256, 0, stream>>>(assign, bias);
  colsum_k<<<64, 256, 0, stream>>>(assign, cs);
  make_sp_all<<<256, 256, 0, stream>>>(assign, cs, spb, spTpan, &scal[1]);

  // G4: features_pooled partials = spT @ F (16 z-chunks, plain f32 stores)
  gemm2<false, false, 0, 2><<<dim3(8, 1, 16), 256, 0, stream>>>(
      spTpan, 256, F, Dd, fp_part, Dd, Nn / 16, 131072, nullptr, 1);
  // G5: spTsp partials = spT @ sp
  gemm2<true, false, 0, 2><<<dim3(4, 1, 16), 256, 0, stream>>>(
      spTpan, 256, spb, Kk, ss_part, Kk, Nn / 16, 65536, nullptr, 1);
  // G2: P = spT @ A: 8 bf16 partials + fused sum(A^2), XCD-chunked, 4 blk/CU
  gemm2<false, true, 1, 4><<<dim3(128, 1, 8), 256, 0, stream>>>(
      spTpan, 256, Adj, Nn, parts, Nn, Nn / 8, (size_t)Kk * Nn, &scal[0], 1);
  combine_P<<<1024, 256, 0, stream>>>(parts, Ppan);
  // G3: adjacency_pooled partials = P @ sp
  gemm2<true, false, 0, 2><<<dim3(4, 1, 16), 256, 0, stream>>>(
      Ppan, 256, spb, Kk, ap_part, Kk, Nn / 16, 65536, nullptr, 1);

  combine3<<<1024, 256, 0, stream>>>(fp_part, ss_part, ap_part, fpool, apool, scal);
  finalize_k<<<1, 64, 0, stream>>>(scal, olink, oent);
}